// Round 10
// baseline (227.616 us; speedup 1.0000x reference)
//
#include <hip/hip_runtime.h>
#include <cstdint>

typedef __attribute__((ext_vector_type(8))) short bf16x8;
typedef __attribute__((ext_vector_type(4))) float f32x4;
typedef __attribute__((ext_vector_type(4))) unsigned int u32x4;

#define DEV static __device__ __forceinline__

DEV unsigned short f2bf(float f) {
  unsigned int u = __builtin_bit_cast(unsigned int, f);
  u += 0x7FFFu + ((u >> 16) & 1u);
  return (unsigned short)(u >> 16);
}
#if __has_builtin(__builtin_amdgcn_cvt_pk_bf16_f32)
DEV unsigned int pkbf(float a, float b) {
  auto v = __builtin_amdgcn_cvt_pk_bf16_f32(a, b);
  return __builtin_bit_cast(unsigned int, v);
}
#else
DEV unsigned int pkbf(float a, float b) {
  return (unsigned int)f2bf(a) | ((unsigned int)f2bf(b) << 16);
}
#endif
#if __has_builtin(__builtin_amdgcn_exp2f)
#define EXP2(x) __builtin_amdgcn_exp2f(x)
#else
#define EXP2(x) exp2f(x)
#endif
DEV float bfl(unsigned int u) { return __builtin_bit_cast(float, u << 16); }
DEV float bfh(unsigned int u) { return __builtin_bit_cast(float, u & 0xFFFF0000u); }

DEV void async_copy16(const unsigned short* g, unsigned short* l) {
  __builtin_amdgcn_global_load_lds(
      (const __attribute__((address_space(1))) unsigned int*)(uintptr_t)g,
      (__attribute__((address_space(3))) unsigned int*)(uintptr_t)l,
      16, 0, 0);
}

// P-fragment lane redistribution for PV (T12). See R1 derivation.
#if __has_builtin(__builtin_amdgcn_permlane32_swap) && \
    __has_builtin(__builtin_amdgcn_permlane16_swap)
DEV void pswap(unsigned a, unsigned b, unsigned& w0, unsigned& w2, int lane) {
  (void)lane;
  auto pq = __builtin_amdgcn_permlane32_swap((int)a, (int)b, false, false);
  auto wz = __builtin_amdgcn_permlane16_swap(pq[0], pq[1], false, false);
  w0 = (unsigned)wz[0];
  w2 = (unsigned)wz[1];
}
#else
DEV void pswap(unsigned a, unsigned b, unsigned& w0, unsigned& w2, int lane) {
  int q = lane >> 4, l = lane & 15;
  int src0 = ((q & 1) << 5) + l;          // quads {0,2} of the source half
  int a0 = __shfl((int)a, src0), b0 = __shfl((int)b, src0);
  int a2 = __shfl((int)a, src0 + 16), b2 = __shfl((int)b, src0 + 16);
  w0 = (unsigned)(q < 2 ? a0 : b0);
  w2 = (unsigned)(q < 2 ? a2 : b2);
}
#endif

// ---------------------------------------------------------------------------
// cvt8: fp32 -> bf16 for wq,wk,wv,wo (ws elem [0,4M)) and x_q,x_kv
// (d_out bf16 view: xqb@[0,4M), xkvb@[4M,8M)). 3M threads, float4 each.
// ---------------------------------------------------------------------------
__global__ __launch_bounds__(256) void cvt8(
    const float* __restrict__ w0, const float* __restrict__ w1,
    const float* __restrict__ w2, const float* __restrict__ w3,
    const float* __restrict__ x0, const float* __restrict__ x1,
    unsigned short* __restrict__ wsb, unsigned short* __restrict__ xb)
{
  int id = blockIdx.x * 256 + threadIdx.x;      // 0 .. 3M-1
  const float* src;
  unsigned short* dp;
  int off;
  if (id < (1 << 20)) {
    int m = id >> 18;
    off = (id & 0x3FFFF) << 2;
    src = m == 0 ? w0 : m == 1 ? w1 : m == 2 ? w2 : w3;
    dp = wsb + (((size_t)m) << 20) + off;
  } else {
    int id2 = id - (1 << 20);
    int m = id2 >> 20;
    off = (id2 & 0xFFFFF) << 2;
    src = m ? x1 : x0;
    dp = xb + (((size_t)m) << 22) + off;
  }
  float4 v = *(const float4*)(src + off);
  uint2 o;
  o.x = pkbf(v.x, v.y);
  o.y = pkbf(v.z, v.w);
  *(uint2*)dp = o;
}

// ---------------------------------------------------------------------------
// QKV projection (R9, verified): per-z 64x128 tiles, grid 1536 (6 blocks/CU),
// 2-phase double-buffer, chunk swizzle, XCD-chunked decode. z<2 -> [bh][s][64]
// with RoPE fused in the epilogue (sincosf SINE-FIRST); Q scaled by
// 0.125*log2(e). z==2 -> V^T [bh][hd][s].
// ---------------------------------------------------------------------------
__global__ __launch_bounds__(256) void gemm_qkv_bf(
    const unsigned short* __restrict__ xqb,
    const unsigned short* __restrict__ xkvb,
    const unsigned short* __restrict__ wbase,
    const float* __restrict__ bq, const float* __restrict__ bk,
    const float* __restrict__ bv,
    unsigned short* __restrict__ outq, unsigned short* __restrict__ outk,
    unsigned short* __restrict__ outvT)
{
  constexpr int K = 1024;
  __shared__ unsigned short As[2][64 * 32];
  __shared__ unsigned short Bs[2][128 * 32];
  const int id = blockIdx.x;
  const int sw_id = (id & 7) * 192 + (id >> 3);
  const int z = sw_id >> 9;                      // 512 tiles per z
  const int r = sw_id & 511;
  const int mBase = (r >> 3) << 6, nBase = (r & 7) << 7;

  const unsigned short* X = (z == 0) ? xqb : xkvb;
  const unsigned short* Wb = wbase + (((size_t)z) << 20);
  const float* bias = (z == 0) ? bq : (z == 1) ? bk : bv;

  const int tid = threadIdx.x;
  const int wave = tid >> 6, lane = tid & 63;
  const int quad = lane >> 4, l16 = lane & 15;
  const int wm = (wave >> 1) << 5, wn = (wave & 1) << 6;

  const int La = tid, ra = La >> 2, ca = ((La & 3) ^ (ra & 3)) << 3;
  const int Lb1 = 256 + tid, rb1 = Lb1 >> 2, cb1 = ((Lb1 & 3) ^ (rb1 & 3)) << 3;

  f32x4 acc[2][4] = {};

  async_copy16(X + (size_t)(mBase + ra) * K + ca, &As[0][La * 8]);
  async_copy16(Wb + (size_t)(nBase + ra) * K + ca, &Bs[0][La * 8]);
  async_copy16(Wb + (size_t)(nBase + rb1) * K + cb1, &Bs[0][Lb1 * 8]);
  __syncthreads();

  const int sw = (quad ^ (l16 & 3)) << 3;
  for (int it = 0; it < 32; ++it) {
    const int cur = it & 1;
    if (it < 31) {
      const int k0 = (it + 1) * 32;
      async_copy16(X + (size_t)(mBase + ra) * K + k0 + ca, &As[cur ^ 1][La * 8]);
      async_copy16(Wb + (size_t)(nBase + ra) * K + k0 + ca, &Bs[cur ^ 1][La * 8]);
      async_copy16(Wb + (size_t)(nBase + rb1) * K + k0 + cb1, &Bs[cur ^ 1][Lb1 * 8]);
    }
    bf16x8 af[2], bff[4];
#pragma unroll
    for (int t = 0; t < 2; ++t)
      af[t] = *(const bf16x8*)&As[cur][(wm + t * 16 + l16) * 32 + sw];
#pragma unroll
    for (int t = 0; t < 4; ++t)
      bff[t] = *(const bf16x8*)&Bs[cur][(wn + t * 16 + l16) * 32 + sw];
#pragma unroll
    for (int mt = 0; mt < 2; ++mt)
#pragma unroll
      for (int nt = 0; nt < 4; ++nt)
        acc[mt][nt] = __builtin_amdgcn_mfma_f32_16x16x32_bf16(af[mt], bff[nt], acc[mt][nt], 0, 0, 0);
    __syncthreads();
  }

  if (z < 2) {
    unsigned short* out = z ? outk : outq;
    const float qs = z ? 1.0f : 0.18033688011112042f;  // 0.125*log2(e)
    const int sBlk = (mBase & 2047) + wm + quad * 4;   // s at mt=0, j=0
#pragma unroll
    for (int nt = 0; nt < 4; ++nt) {
      int n = nBase + wn + nt * 16 + l16;
      float bv2 = bias[n];
      int h = n >> 6, hd = n & 63;
      int i = hd >> 1;
      int parity = n & 1;
      float f = exp2f(-(float)i * 0.4152410118609203f);
      float sf, cf;
      sincosf(f, &sf, &cf);
#pragma unroll
      for (int mt = 0; mt < 2; ++mt) {
        float ang = (float)(sBlk + mt * 16) * f;
        float s, c;
        sincosf(ang, &s, &c);
#pragma unroll
        for (int j = 0; j < 4; ++j) {
          float v = acc[mt][nt][j] + bv2;
          float pv = __shfl_xor(v, 1);
          float ce = c * qs;
          float se = (parity ? s : -s) * qs;
          float outv = v * ce + pv * se;
          int m = mBase + wm + mt * 16 + quad * 4 + j;
          int b = m >> 11, sv = m & 2047;
          out[(((size_t)(b * 16 + h) * 2048 + sv) << 6) + hd] = f2bf(outv);
          float c2 = c * cf - s * sf;
          s = s * cf + c * sf;
          c = c2;
        }
      }
    }
  } else {
#pragma unroll
    for (int nt = 0; nt < 4; ++nt) {
      int n = nBase + wn + nt * 16 + l16;
      float bv2 = bias[n];
      int h = n >> 6, hd = n & 63;
#pragma unroll
      for (int mt = 0; mt < 2; ++mt) {
        int m0 = mBase + wm + mt * 16 + quad * 4;
        int b = m0 >> 11, s = m0 & 2047;
        uint2 o;
        o.x = pkbf(acc[mt][nt][0] + bv2, acc[mt][nt][1] + bv2);
        o.y = pkbf(acc[mt][nt][2] + bv2, acc[mt][nt][3] + bv2);
        *(uint2*)&outvT[(((size_t)(b * 16 + h) * 64 + hd) << 11) + s] = o;
      }
    }
  }
}

// ---------------------------------------------------------------------------
// Flash attention v9: identical per-wave math to v8 (ones-MFMA l, deferred
// PV, V triple-buffer, rule-21 swizzle, in-reg P, setprio) but 8 WAVES per
// block (512 threads): one K/V staging serves 8 q-tiles instead of 4, so
// per-thread staging halves (2 async_copy16/tile vs 4) and staging address
// VALU halves. Grid 512 = bh(32) x qt(8) x kvs(2) -> 2 blocks/CU x 8 waves
// = 16 waves/CU (same TLP as v8). LDS 40KB unchanged.
// ---------------------------------------------------------------------------
__global__ __launch_bounds__(512) void attn_v9(
    const unsigned short* __restrict__ Qg,
    const unsigned short* __restrict__ Kg,
    const unsigned short* __restrict__ VT,
    unsigned short* __restrict__ Opart,   // [kvs][4096][1024] bf16
    float* __restrict__ lbuf)             // [kvs][32][2048]
{
  __shared__ unsigned short Ks[2][64 * 64];
  __shared__ unsigned short Vs[3][64 * 64];
  const int tid = threadIdx.x, wave = tid >> 6, lane = tid & 63;
  const int quad = lane >> 4, l16 = lane & 15;
  const int bh = blockIdx.x & 31;            // id%8 = bh%8 -> same-bh on XCD
  const int qt = (blockIdx.x >> 5) & 7;
  const int kvs = blockIdx.x >> 8;           // 0/1
  const int q0 = qt * 256 + wave * 32;
  const unsigned short* Qb = Qg + ((size_t)bh << 17);
  const unsigned short* Kb = Kg + ((size_t)bh << 17);
  const unsigned short* Vb = VT + ((size_t)bh << 17);

  // staging: 1 chunk of K + 1 chunk of V per thread (512 threads = 512 chunks)
  const int L0 = tid;
  const int r0 = L0 >> 3;
  const int c0 = ((L0 & 7) ^ (r0 & 7)) << 3;

  bf16x8 qf[2][2];
#pragma unroll
  for (int mq = 0; mq < 2; ++mq)
#pragma unroll
    for (int kd = 0; kd < 2; ++kd)
      qf[mq][kd] = *(const bf16x8*)(Qb + (size_t)(q0 + mq * 16 + l16) * 64 + kd * 32 + quad * 8);

  bf16x8 onesf;
#pragma unroll
  for (int i = 0; i < 8; ++i) onesf[i] = (short)0x3F80;

  f32x4 oacc[4][2] = {};                     // [th(hd)][mq(q)]
  f32x4 laccv[2] = {};                       // l via ones-MFMA, [mq]
  bf16x8 pfp[2][2];                          // carried P frags [ks][mq]

  const int kvbeg = kvs << 10;
  const int swz = l16 & 7;

  async_copy16(Kb + (size_t)(kvbeg + r0) * 64 + c0, &Ks[0][L0 * 8]);
  async_copy16(Vb + (size_t)r0 * 2048 + kvbeg + c0, &Vs[0][L0 * 8]);
  __syncthreads();

  for (int t = 0; t < 16; ++t) {
    const int kcur = t & 1;
    if (t < 15) {                            // stage tile t+1
      const int kv0 = kvbeg + (t + 1) * 64;
      async_copy16(Kb + (size_t)(kv0 + r0) * 64 + c0, &Ks[kcur ^ 1][L0 * 8]);
      async_copy16(Vb + (size_t)r0 * 2048 + kv0 + c0, &Vs[(t + 1) % 3][L0 * 8]);
    }

    // --- deferred PV(t-1): fills the QK ds_read shadow ---
    if (t > 0) {
      const unsigned short* Vp = Vs[(t - 1) % 3];
      __builtin_amdgcn_s_setprio(1);
#pragma unroll
      for (int ks = 0; ks < 2; ++ks) {
#pragma unroll
        for (int th = 0; th < 4; ++th) {
          bf16x8 vf = *(const bf16x8*)&Vp[(th * 16 + l16) * 64 + (((ks * 4 + quad) ^ swz) << 3)];
#pragma unroll
          for (int mq = 0; mq < 2; ++mq)
            oacc[th][mq] = __builtin_amdgcn_mfma_f32_16x16x32_bf16(vf, pfp[ks][mq], oacc[th][mq], 0, 0, 0);
        }
#pragma unroll
        for (int mq = 0; mq < 2; ++mq)
          laccv[mq] = __builtin_amdgcn_mfma_f32_16x16x32_bf16(onesf, pfp[ks][mq], laccv[mq], 0, 0, 0);
      }
      __builtin_amdgcn_s_setprio(0);
    }

    // --- S^T = K·Q^T (swizzled ds_read) ---
    const unsigned short* Kc = Ks[kcur];
    f32x4 st[4][2] = {};
    __builtin_amdgcn_s_setprio(1);
#pragma unroll
    for (int kd = 0; kd < 2; ++kd)
#pragma unroll
      for (int tk = 0; tk < 4; ++tk) {
        bf16x8 kf = *(const bf16x8*)&Kc[(tk * 16 + l16) * 64 + (((kd * 4 + quad) ^ swz) << 3)];
#pragma unroll
        for (int mq = 0; mq < 2; ++mq)
          st[tk][mq] = __builtin_amdgcn_mfma_f32_16x16x32_bf16(kf, qf[mq][kd], st[tk][mq], 0, 0, 0);
      }
    __builtin_amdgcn_s_setprio(0);

    // --- static softmax: p = exp2(st); pack P frags for next-iter PV ---
#pragma unroll
    for (int mq = 0; mq < 2; ++mq)
#pragma unroll
      for (int tk = 0; tk < 4; ++tk)
#pragma unroll
        for (int jr = 0; jr < 4; ++jr)
          st[tk][mq][jr] = EXP2(st[tk][mq][jr]);

#pragma unroll
    for (int ks = 0; ks < 2; ++ks)
#pragma unroll
      for (int mq = 0; mq < 2; ++mq) {
        u32x4 pw;
#pragma unroll
        for (int w = 0; w < 2; ++w) {
          unsigned a = pkbf(st[2 * ks][mq][2 * w], st[2 * ks][mq][2 * w + 1]);
          unsigned b = pkbf(st[2 * ks + 1][mq][2 * w], st[2 * ks + 1][mq][2 * w + 1]);
          unsigned w0, w2;
          pswap(a, b, w0, w2, lane);
          pw[w] = w0;
          pw[w + 2] = w2;
        }
        pfp[ks][mq] = __builtin_bit_cast(bf16x8, pw);
      }

    __syncthreads();   // orders stage(t+1) vs reads at t+1; protects buffers
  }

  // --- final PV(15): V tile 15 lives in Vs[0] ---
  {
    const unsigned short* Vp = Vs[15 % 3];
    __builtin_amdgcn_s_setprio(1);
#pragma unroll
    for (int ks = 0; ks < 2; ++ks) {
#pragma unroll
      for (int th = 0; th < 4; ++th) {
        bf16x8 vf = *(const bf16x8*)&Vp[(th * 16 + l16) * 64 + (((ks * 4 + quad) ^ swz) << 3)];
#pragma unroll
        for (int mq = 0; mq < 2; ++mq)
          oacc[th][mq] = __builtin_amdgcn_mfma_f32_16x16x32_bf16(vf, pfp[ks][mq], oacc[th][mq], 0, 0, 0);
      }
#pragma unroll
      for (int mq = 0; mq < 2; ++mq)
        laccv[mq] = __builtin_amdgcn_mfma_f32_16x16x32_bf16(onesf, pfp[ks][mq], laccv[mq], 0, 0, 0);
    }
    __builtin_amdgcn_s_setprio(0);
  }

  // --- epilogue: write partial l (quad 0) and unnormalized partial O ---
  const int b = bh >> 4, h = bh & 15;
  unsigned short* Od = Opart + (((size_t)kvs) << 22);
#pragma unroll
  for (int mq = 0; mq < 2; ++mq) {
    int s = q0 + mq * 16 + l16;
    if (quad == 0)
      lbuf[(kvs * 32 + bh) * 2048 + s] = laccv[mq][0];
#pragma unroll
    for (int th = 0; th < 4; ++th) {
      uint2 o;
      o.x = pkbf(oacc[th][mq][0], oacc[th][mq][1]);
      o.y = pkbf(oacc[th][mq][2], oacc[th][mq][3]);
      *(uint2*)&Od[((size_t)(b * 2048 + s) << 10) + h * 64 + th * 16 + quad * 4] = o;
    }
  }
}

// ---------------------------------------------------------------------------
// Combine the two kv-split partials: ctx = (OA + OB) / (lA + lB).
// ---------------------------------------------------------------------------
__global__ __launch_bounds__(256) void combine_kernel(
    const unsigned short* __restrict__ Opart, const float* __restrict__ lbuf,
    unsigned short* __restrict__ ctx)
{
  int idx = blockIdx.x * 256 + threadIdx.x;   // 0 .. 2M-1
  int m = idx >> 9;                           // row 0..4095
  int c2 = idx & 511;
  int b = m >> 11, s = m & 2047;
  int h = c2 >> 5;
  int bh = b * 16 + h;
  float la = lbuf[bh * 2048 + s];
  float lb = lbuf[(32 + bh) * 2048 + s];
  float r = 1.0f / (la + lb);
  unsigned int ua = ((const unsigned int*)Opart)[idx];
  unsigned int ub = ((const unsigned int*)Opart)[(1u << 21) + idx];
  float o0 = (bfl(ua) + bfl(ub)) * r;
  float o1 = (bfh(ua) + bfh(ub)) * r;
  ((unsigned int*)ctx)[idx] = pkbf(o0, o1);
}

// ---------------------------------------------------------------------------
// O-projection (R7, passed three times): triple-buffered K-tiles with
// counted vmcnt + raw s_barrier. 64x128 tile, chunked XCD swizzle.
// fp32 out + bias.
// ---------------------------------------------------------------------------
__global__ __launch_bounds__(256) void gemm_o_bf(
    const unsigned short* __restrict__ X,
    const unsigned short* __restrict__ Wb,
    const float* __restrict__ bias,
    float* __restrict__ out)
{
  constexpr int K = 1024;
  __shared__ unsigned short As[3][64 * 32];
  __shared__ unsigned short Bs[3][128 * 32];
  const int id = blockIdx.x;
  const int sw_id = (id & 7) * 64 + (id >> 3);   // 512 = 8 x 64, bijective
  const int mBase = (sw_id >> 3) << 6, nBase = (sw_id & 7) << 7;

  const int tid = threadIdx.x;
  const int wave = tid >> 6, lane = tid & 63;
  const int quad = lane >> 4, l16 = lane & 15;
  const int wm = (wave >> 1) << 5, wn = (wave & 1) << 6;

  const int La = tid, ra = La >> 2, ca = ((La & 3) ^ (ra & 3)) << 3;
  const int Lb1 = 256 + tid, rb1 = Lb1 >> 2, cb1 = ((Lb1 & 3) ^ (rb1 & 3)) << 3;

  f32x4 acc[2][4] = {};

#define O_STAGE(kt, bi)                                                        \
  do {                                                                         \
    const int k0_ = (kt) * 32;                                                 \
    async_copy16(X + (size_t)(mBase + ra) * K + k0_ + ca, &As[bi][La * 8]);    \
    async_copy16(Wb + (size_t)(nBase + ra) * K + k0_ + ca, &Bs[bi][La * 8]);   \
    async_copy16(Wb + (size_t)(nBase + rb1) * K + k0_ + cb1, &Bs[bi][Lb1 * 8]);\
  } while (0)

  O_STAGE(0, 0);
  O_STAGE(1, 1);                   // 6 loads in flight

  const int sw = (quad ^ (l16 & 3)) << 3;
  for (int it = 0; it < 32; ++it) {
    if (it < 31)
      asm volatile("s_waitcnt vmcnt(3)" ::: "memory");   // oldest stage done
    else
      asm volatile("s_waitcnt vmcnt(0)" ::: "memory");
    __builtin_amdgcn_s_barrier();
    if (it < 30)
      O_STAGE(it + 2, (it + 2) % 3);
    const int cur = it % 3;
    bf16x8 af[2], bff[4];
#pragma unroll
    for (int t = 0; t < 2; ++t)
      af[t] = *(const bf16x8*)&As[cur][(wm + t * 16 + l16) * 32 + sw];
#pragma unroll
    for (int t = 0; t < 4; ++t)
      bff[t] = *(const bf16x8*)&Bs[cur][(wn + t * 16 + l16) * 32 + sw];
#pragma unroll
    for (int mt = 0; mt < 2; ++mt)
#pragma unroll
      for (int nt = 0; nt < 4; ++nt)
        acc[mt][nt] = __builtin_amdgcn_mfma_f32_16x16x32_bf16(af[mt], bff[nt], acc[mt][nt], 0, 0, 0);
  }
#undef O_STAGE

#pragma unroll
  for (int nt = 0; nt < 4; ++nt) {
    int n = nBase + wn + nt * 16 + l16;
    float bv = bias[n];
#pragma unroll
    for (int mt = 0; mt < 2; ++mt) {
#pragma unroll
      for (int j = 0; j < 4; ++j) {
        int m = mBase + wm + mt * 16 + quad * 4 + j;
        out[((size_t)m << 10) + n] = acc[mt][nt][j] + bv;
      }
    }
  }
}

// ---------------------------------------------------------------------------
// Memory plan (elem = bf16; 1M = 1<<20 elem = 2 MB):
//  ws (32 MB = 16M elem): w4 [0,4M) | k [4M,8M) | vT [8M,12M) | q [12M,16M)
//    - lbuf (fp32, 512 KB) overlays [0,256K elem) — wq dead by then
//    - ctx [12M,16M) overlays q after attn (q dead)
//  d_out (16 MB = 8M elem bf16 view): xqb [0,4M) | xkvb [4M,8M)
//    - attn partials OA [0,4M), OB [4M,8M) overlay (xqb/xkvb dead)
//    - final fp32 out overwrites everything (partials dead)
// All phases are stream-ordered; no region is concurrently read+written.
// RoPE is fused into gemm_qkv's epilogue (no separate pass).
// ---------------------------------------------------------------------------
extern "C" void kernel_launch(void* const* d_in, const int* in_sizes, int n_in,
                              void* d_out, int out_size, void* d_ws, size_t ws_size,
                              hipStream_t stream) {
  const float* x_q  = (const float*)d_in[0];
  const float* x_kv = (const float*)d_in[1];
  const float* wq   = (const float*)d_in[2];
  const float* bq   = (const float*)d_in[3];
  const float* wk   = (const float*)d_in[4];
  const float* bk   = (const float*)d_in[5];
  const float* wv   = (const float*)d_in[6];
  const float* bv   = (const float*)d_in[7];
  const float* wo   = (const float*)d_in[8];
  const float* bo   = (const float*)d_in[9];

  unsigned short* base = (unsigned short*)d_ws;
  unsigned short* ob   = (unsigned short*)d_out;

  unsigned short* wob  = base + (3u << 20);
  unsigned short* k    = base + (4u << 20);
  unsigned short* vT   = base + (8u << 20);
  unsigned short* q    = base + (12u << 20);
  unsigned short* ctx  = q;                    // overlays q after attn
  float*          lbuf = (float*)d_ws;         // overlays wq (dead)
  unsigned short* xqb  = ob;
  unsigned short* xkvb = ob + (4u << 20);
  unsigned short* Opart = ob;                  // overlays xqb/xkvb (dead)
  float* out = (float*)d_out;

  cvt8<<<12288, 256, 0, stream>>>(wq, wk, wv, wo, x_q, x_kv, base, ob);
  gemm_qkv_bf<<<1536, 256, 0, stream>>>(xqb, xkvb, base, bq, bk, bv, q, k, vT);
  attn_v9<<<512, 512, 0, stream>>>(q, k, vT, Opart, lbuf);
  combine_kernel<<<8192, 256, 0, stream>>>(Opart, lbuf, ctx);
  gemm_o_bf<<<512, 256, 0, stream>>>(ctx, wob, bo, out);
}

// Round 11
// 217.149 us; speedup vs baseline: 1.0482x; 1.0482x over previous
//
#include <hip/hip_runtime.h>
#include <cstdint>

typedef __attribute__((ext_vector_type(8))) short bf16x8;
typedef __attribute__((ext_vector_type(4))) float f32x4;
typedef __attribute__((ext_vector_type(4))) unsigned int u32x4;

#define DEV static __device__ __forceinline__

DEV unsigned short f2bf(float f) {
  unsigned int u = __builtin_bit_cast(unsigned int, f);
  u += 0x7FFFu + ((u >> 16) & 1u);
  return (unsigned short)(u >> 16);
}
#if __has_builtin(__builtin_amdgcn_cvt_pk_bf16_f32)
DEV unsigned int pkbf(float a, float b) {
  auto v = __builtin_amdgcn_cvt_pk_bf16_f32(a, b);
  return __builtin_bit_cast(unsigned int, v);
}
#else
DEV unsigned int pkbf(float a, float b) {
  return (unsigned int)f2bf(a) | ((unsigned int)f2bf(b) << 16);
}
#endif
#if __has_builtin(__builtin_amdgcn_exp2f)
#define EXP2(x) __builtin_amdgcn_exp2f(x)
#else
#define EXP2(x) exp2f(x)
#endif
DEV float bfl(unsigned int u) { return __builtin_bit_cast(float, u << 16); }
DEV float bfh(unsigned int u) { return __builtin_bit_cast(float, u & 0xFFFF0000u); }

DEV void async_copy16(const unsigned short* g, unsigned short* l) {
  __builtin_amdgcn_global_load_lds(
      (const __attribute__((address_space(1))) unsigned int*)(uintptr_t)g,
      (__attribute__((address_space(3))) unsigned int*)(uintptr_t)l,
      16, 0, 0);
}

// P-fragment lane redistribution for PV (T12). See R1 derivation.
#if __has_builtin(__builtin_amdgcn_permlane32_swap) && \
    __has_builtin(__builtin_amdgcn_permlane16_swap)
DEV void pswap(unsigned a, unsigned b, unsigned& w0, unsigned& w2, int lane) {
  (void)lane;
  auto pq = __builtin_amdgcn_permlane32_swap((int)a, (int)b, false, false);
  auto wz = __builtin_amdgcn_permlane16_swap(pq[0], pq[1], false, false);
  w0 = (unsigned)wz[0];
  w2 = (unsigned)wz[1];
}
#else
DEV void pswap(unsigned a, unsigned b, unsigned& w0, unsigned& w2, int lane) {
  int q = lane >> 4, l = lane & 15;
  int src0 = ((q & 1) << 5) + l;          // quads {0,2} of the source half
  int a0 = __shfl((int)a, src0), b0 = __shfl((int)b, src0);
  int a2 = __shfl((int)a, src0 + 16), b2 = __shfl((int)b, src0 + 16);
  w0 = (unsigned)(q < 2 ? a0 : b0);
  w2 = (unsigned)(q < 2 ? a2 : b2);
}
#endif

// ---------------------------------------------------------------------------
// cvt8: fp32 -> bf16 for wq,wk,wv,wo (ws elem [0,4M)) and x_q,x_kv
// (d_out bf16 view: xqb@[0,4M), xkvb@[4M,8M)). 3M threads, float4 each.
// ---------------------------------------------------------------------------
__global__ __launch_bounds__(256) void cvt8(
    const float* __restrict__ w0, const float* __restrict__ w1,
    const float* __restrict__ w2, const float* __restrict__ w3,
    const float* __restrict__ x0, const float* __restrict__ x1,
    unsigned short* __restrict__ wsb, unsigned short* __restrict__ xb)
{
  int id = blockIdx.x * 256 + threadIdx.x;      // 0 .. 3M-1
  const float* src;
  unsigned short* dp;
  int off;
  if (id < (1 << 20)) {
    int m = id >> 18;
    off = (id & 0x3FFFF) << 2;
    src = m == 0 ? w0 : m == 1 ? w1 : m == 2 ? w2 : w3;
    dp = wsb + (((size_t)m) << 20) + off;
  } else {
    int id2 = id - (1 << 20);
    int m = id2 >> 20;
    off = (id2 & 0xFFFFF) << 2;
    src = m ? x1 : x0;
    dp = xb + (((size_t)m) << 22) + off;
  }
  float4 v = *(const float4*)(src + off);
  uint2 o;
  o.x = pkbf(v.x, v.y);
  o.y = pkbf(v.z, v.w);
  *(uint2*)dp = o;
}

// ---------------------------------------------------------------------------
// QKV projection. R11: BK=32 -> BK=64 with 128B LDS rows + 8-chunk XOR
// (^row&7), the layout measured conflict-free in attn since R1. BK=32's
// 64B rows force 8-way bank aliasing (rows span only 16 banks) — no 4-chunk
// permutation can fix it; 4.7M conflict cycles measured at R10. Barriers
// halve (32->16 iters). 64x128 tile, 2-phase double-buffer, XCD-chunked
// decode, grid 1536 -> 3 blocks/CU at 48KB LDS. z<2 -> [bh][s][64] with
// RoPE fused in the epilogue (sincosf SINE-FIRST); Q scaled by
// 0.125*log2(e). z==2 -> V^T [bh][hd][s].
// ---------------------------------------------------------------------------
__global__ __launch_bounds__(256) void gemm_qkv_bf(
    const unsigned short* __restrict__ xqb,
    const unsigned short* __restrict__ xkvb,
    const unsigned short* __restrict__ wbase,
    const float* __restrict__ bq, const float* __restrict__ bk,
    const float* __restrict__ bv,
    unsigned short* __restrict__ outq, unsigned short* __restrict__ outk,
    unsigned short* __restrict__ outvT)
{
  constexpr int K = 1024;
  __shared__ unsigned short As[2][64 * 64];     // 8 KB / buf
  __shared__ unsigned short Bs[2][128 * 64];    // 16 KB / buf
  const int id = blockIdx.x;
  const int sw_id = (id & 7) * 192 + (id >> 3);
  const int z = sw_id >> 9;                      // 512 tiles per z
  const int r = sw_id & 511;
  const int mBase = (r >> 3) << 6, nBase = (r & 7) << 7;

  const unsigned short* X = (z == 0) ? xqb : xkvb;
  const unsigned short* Wb = wbase + (((size_t)z) << 20);
  const float* bias = (z == 0) ? bq : (z == 1) ? bk : bv;

  const int tid = threadIdx.x;
  const int wave = tid >> 6, lane = tid & 63;
  const int quad = lane >> 4, l16 = lane & 15;
  const int wm = (wave >> 1) << 5, wn = (wave & 1) << 6;

  // staging (16B chunks, 8 per 64-elem row; LDS linear, source pre-swizzled):
  // A: 512 chunks = 2/thread; B: 1024 chunks = 4/thread.
  const int La0 = tid, La1 = 256 + tid;
  const int ra0 = La0 >> 3, ca0 = ((La0 & 7) ^ (ra0 & 7)) << 3;
  const int ra1 = La1 >> 3, ca1 = ((La1 & 7) ^ (ra1 & 7)) << 3;
  const int Lb0 = tid,        rb0 = Lb0 >> 3, cb0 = ((Lb0 & 7) ^ (rb0 & 7)) << 3;
  const int Lb1 = 256 + tid,  rb1 = Lb1 >> 3, cb1 = ((Lb1 & 7) ^ (rb1 & 7)) << 3;
  const int Lb2 = 512 + tid,  rb2 = Lb2 >> 3, cb2 = ((Lb2 & 7) ^ (rb2 & 7)) << 3;
  const int Lb3 = 768 + tid,  rb3 = Lb3 >> 3, cb3 = ((Lb3 & 7) ^ (rb3 & 7)) << 3;

  f32x4 acc[2][4] = {};

#define QKV_STAGE(kt, bi)                                                      \
  do {                                                                         \
    const int k0_ = (kt) * 64;                                                 \
    async_copy16(X + (size_t)(mBase + ra0) * K + k0_ + ca0, &As[bi][La0 * 8]); \
    async_copy16(X + (size_t)(mBase + ra1) * K + k0_ + ca1, &As[bi][La1 * 8]); \
    async_copy16(Wb + (size_t)(nBase + rb0) * K + k0_ + cb0, &Bs[bi][Lb0 * 8]);\
    async_copy16(Wb + (size_t)(nBase + rb1) * K + k0_ + cb1, &Bs[bi][Lb1 * 8]);\
    async_copy16(Wb + (size_t)(nBase + rb2) * K + k0_ + cb2, &Bs[bi][Lb2 * 8]);\
    async_copy16(Wb + (size_t)(nBase + rb3) * K + k0_ + cb3, &Bs[bi][Lb3 * 8]);\
  } while (0)

  QKV_STAGE(0, 0);
  __syncthreads();

  const int swz = l16 & 7;
  for (int it = 0; it < 16; ++it) {
    const int cur = it & 1;
    if (it < 15)
      QKV_STAGE(it + 1, cur ^ 1);
#pragma unroll
    for (int kd = 0; kd < 2; ++kd) {
      const int cs = (((kd * 4 + quad) ^ swz) << 3);
      bf16x8 af[2], bff[4];
#pragma unroll
      for (int t = 0; t < 2; ++t)
        af[t] = *(const bf16x8*)&As[cur][(wm + t * 16 + l16) * 64 + cs];
#pragma unroll
      for (int t = 0; t < 4; ++t)
        bff[t] = *(const bf16x8*)&Bs[cur][(wn + t * 16 + l16) * 64 + cs];
#pragma unroll
      for (int mt = 0; mt < 2; ++mt)
#pragma unroll
        for (int nt = 0; nt < 4; ++nt)
          acc[mt][nt] = __builtin_amdgcn_mfma_f32_16x16x32_bf16(af[mt], bff[nt], acc[mt][nt], 0, 0, 0);
    }
    __syncthreads();   // drains prefetch vmcnt + protects cur buffer
  }
#undef QKV_STAGE

  if (z < 2) {
    unsigned short* out = z ? outk : outq;
    const float qs = z ? 1.0f : 0.18033688011112042f;  // 0.125*log2(e)
    const int sBlk = (mBase & 2047) + wm + quad * 4;   // s at mt=0, j=0
#pragma unroll
    for (int nt = 0; nt < 4; ++nt) {
      int n = nBase + wn + nt * 16 + l16;
      float bv2 = bias[n];
      int h = n >> 6, hd = n & 63;
      int i = hd >> 1;
      int parity = n & 1;
      float f = exp2f(-(float)i * 0.4152410118609203f);
      float sf, cf;
      sincosf(f, &sf, &cf);
#pragma unroll
      for (int mt = 0; mt < 2; ++mt) {
        float ang = (float)(sBlk + mt * 16) * f;
        float s, c;
        sincosf(ang, &s, &c);
#pragma unroll
        for (int j = 0; j < 4; ++j) {
          float v = acc[mt][nt][j] + bv2;
          float pv = __shfl_xor(v, 1);
          float ce = c * qs;
          float se = (parity ? s : -s) * qs;
          float outv = v * ce + pv * se;
          int m = mBase + wm + mt * 16 + quad * 4 + j;
          int b = m >> 11, sv = m & 2047;
          out[(((size_t)(b * 16 + h) * 2048 + sv) << 6) + hd] = f2bf(outv);
          float c2 = c * cf - s * sf;
          s = s * cf + c * sf;
          c = c2;
        }
      }
    }
  } else {
#pragma unroll
    for (int nt = 0; nt < 4; ++nt) {
      int n = nBase + wn + nt * 16 + l16;
      float bv2 = bias[n];
      int h = n >> 6, hd = n & 63;
#pragma unroll
      for (int mt = 0; mt < 2; ++mt) {
        int m0 = mBase + wm + mt * 16 + quad * 4;
        int b = m0 >> 11, s = m0 & 2047;
        uint2 o;
        o.x = pkbf(acc[mt][nt][0] + bv2, acc[mt][nt][1] + bv2);
        o.y = pkbf(acc[mt][nt][2] + bv2, acc[mt][nt][3] + bv2);
        *(uint2*)&outvT[(((size_t)(b * 16 + h) * 64 + hd) << 11) + s] = o;
      }
    }
  }
}

// ---------------------------------------------------------------------------
// Flash attention v9 (R10, passed): 8 waves/block, ones-MFMA l accumulation,
// deferred PV (V triple-buffer), rule-21 swizzle, in-reg P, setprio.
// Grid 512 = bh(32) x qt(8) x kvs(2) -> 2 blocks/CU x 8 waves.
// ---------------------------------------------------------------------------
__global__ __launch_bounds__(512) void attn_v9(
    const unsigned short* __restrict__ Qg,
    const unsigned short* __restrict__ Kg,
    const unsigned short* __restrict__ VT,
    unsigned short* __restrict__ Opart,   // [kvs][4096][1024] bf16
    float* __restrict__ lbuf)             // [kvs][32][2048]
{
  __shared__ unsigned short Ks[2][64 * 64];
  __shared__ unsigned short Vs[3][64 * 64];
  const int tid = threadIdx.x, wave = tid >> 6, lane = tid & 63;
  const int quad = lane >> 4, l16 = lane & 15;
  const int bh = blockIdx.x & 31;            // id%8 = bh%8 -> same-bh on XCD
  const int qt = (blockIdx.x >> 5) & 7;
  const int kvs = blockIdx.x >> 8;           // 0/1
  const int q0 = qt * 256 + wave * 32;
  const unsigned short* Qb = Qg + ((size_t)bh << 17);
  const unsigned short* Kb = Kg + ((size_t)bh << 17);
  const unsigned short* Vb = VT + ((size_t)bh << 17);

  // staging: 1 chunk of K + 1 chunk of V per thread (512 threads = 512 chunks)
  const int L0 = tid;
  const int r0 = L0 >> 3;
  const int c0 = ((L0 & 7) ^ (r0 & 7)) << 3;

  bf16x8 qf[2][2];
#pragma unroll
  for (int mq = 0; mq < 2; ++mq)
#pragma unroll
    for (int kd = 0; kd < 2; ++kd)
      qf[mq][kd] = *(const bf16x8*)(Qb + (size_t)(q0 + mq * 16 + l16) * 64 + kd * 32 + quad * 8);

  bf16x8 onesf;
#pragma unroll
  for (int i = 0; i < 8; ++i) onesf[i] = (short)0x3F80;

  f32x4 oacc[4][2] = {};                     // [th(hd)][mq(q)]
  f32x4 laccv[2] = {};                       // l via ones-MFMA, [mq]
  bf16x8 pfp[2][2];                          // carried P frags [ks][mq]

  const int kvbeg = kvs << 10;
  const int swz = l16 & 7;

  async_copy16(Kb + (size_t)(kvbeg + r0) * 64 + c0, &Ks[0][L0 * 8]);
  async_copy16(Vb + (size_t)r0 * 2048 + kvbeg + c0, &Vs[0][L0 * 8]);
  __syncthreads();

  for (int t = 0; t < 16; ++t) {
    const int kcur = t & 1;
    if (t < 15) {                            // stage tile t+1
      const int kv0 = kvbeg + (t + 1) * 64;
      async_copy16(Kb + (size_t)(kv0 + r0) * 64 + c0, &Ks[kcur ^ 1][L0 * 8]);
      async_copy16(Vb + (size_t)r0 * 2048 + kv0 + c0, &Vs[(t + 1) % 3][L0 * 8]);
    }

    // --- deferred PV(t-1): fills the QK ds_read shadow ---
    if (t > 0) {
      const unsigned short* Vp = Vs[(t - 1) % 3];
      __builtin_amdgcn_s_setprio(1);
#pragma unroll
      for (int ks = 0; ks < 2; ++ks) {
#pragma unroll
        for (int th = 0; th < 4; ++th) {
          bf16x8 vf = *(const bf16x8*)&Vp[(th * 16 + l16) * 64 + (((ks * 4 + quad) ^ swz) << 3)];
#pragma unroll
          for (int mq = 0; mq < 2; ++mq)
            oacc[th][mq] = __builtin_amdgcn_mfma_f32_16x16x32_bf16(vf, pfp[ks][mq], oacc[th][mq], 0, 0, 0);
        }
#pragma unroll
        for (int mq = 0; mq < 2; ++mq)
          laccv[mq] = __builtin_amdgcn_mfma_f32_16x16x32_bf16(onesf, pfp[ks][mq], laccv[mq], 0, 0, 0);
      }
      __builtin_amdgcn_s_setprio(0);
    }

    // --- S^T = K·Q^T (swizzled ds_read) ---
    const unsigned short* Kc = Ks[kcur];
    f32x4 st[4][2] = {};
    __builtin_amdgcn_s_setprio(1);
#pragma unroll
    for (int kd = 0; kd < 2; ++kd)
#pragma unroll
      for (int tk = 0; tk < 4; ++tk) {
        bf16x8 kf = *(const bf16x8*)&Kc[(tk * 16 + l16) * 64 + (((kd * 4 + quad) ^ swz) << 3)];
#pragma unroll
        for (int mq = 0; mq < 2; ++mq)
          st[tk][mq] = __builtin_amdgcn_mfma_f32_16x16x32_bf16(kf, qf[mq][kd], st[tk][mq], 0, 0, 0);
      }
    __builtin_amdgcn_s_setprio(0);

    // --- static softmax: p = exp2(st); pack P frags for next-iter PV ---
#pragma unroll
    for (int mq = 0; mq < 2; ++mq)
#pragma unroll
      for (int tk = 0; tk < 4; ++tk)
#pragma unroll
        for (int jr = 0; jr < 4; ++jr)
          st[tk][mq][jr] = EXP2(st[tk][mq][jr]);

#pragma unroll
    for (int ks = 0; ks < 2; ++ks)
#pragma unroll
      for (int mq = 0; mq < 2; ++mq) {
        u32x4 pw;
#pragma unroll
        for (int w = 0; w < 2; ++w) {
          unsigned a = pkbf(st[2 * ks][mq][2 * w], st[2 * ks][mq][2 * w + 1]);
          unsigned b = pkbf(st[2 * ks + 1][mq][2 * w], st[2 * ks + 1][mq][2 * w + 1]);
          unsigned w0, w2;
          pswap(a, b, w0, w2, lane);
          pw[w] = w0;
          pw[w + 2] = w2;
        }
        pfp[ks][mq] = __builtin_bit_cast(bf16x8, pw);
      }

    __syncthreads();   // orders stage(t+1) vs reads at t+1; protects buffers
  }

  // --- final PV(15): V tile 15 lives in Vs[0] ---
  {
    const unsigned short* Vp = Vs[15 % 3];
    __builtin_amdgcn_s_setprio(1);
#pragma unroll
    for (int ks = 0; ks < 2; ++ks) {
#pragma unroll
      for (int th = 0; th < 4; ++th) {
        bf16x8 vf = *(const bf16x8*)&Vp[(th * 16 + l16) * 64 + (((ks * 4 + quad) ^ swz) << 3)];
#pragma unroll
        for (int mq = 0; mq < 2; ++mq)
          oacc[th][mq] = __builtin_amdgcn_mfma_f32_16x16x32_bf16(vf, pfp[ks][mq], oacc[th][mq], 0, 0, 0);
      }
#pragma unroll
      for (int mq = 0; mq < 2; ++mq)
        laccv[mq] = __builtin_amdgcn_mfma_f32_16x16x32_bf16(onesf, pfp[ks][mq], laccv[mq], 0, 0, 0);
    }
    __builtin_amdgcn_s_setprio(0);
  }

  // --- epilogue: write partial l (quad 0) and unnormalized partial O ---
  const int b = bh >> 4, h = bh & 15;
  unsigned short* Od = Opart + (((size_t)kvs) << 22);
#pragma unroll
  for (int mq = 0; mq < 2; ++mq) {
    int s = q0 + mq * 16 + l16;
    if (quad == 0)
      lbuf[(kvs * 32 + bh) * 2048 + s] = laccv[mq][0];
#pragma unroll
    for (int th = 0; th < 4; ++th) {
      uint2 o;
      o.x = pkbf(oacc[th][mq][0], oacc[th][mq][1]);
      o.y = pkbf(oacc[th][mq][2], oacc[th][mq][3]);
      *(uint2*)&Od[((size_t)(b * 2048 + s) << 10) + h * 64 + th * 16 + quad * 4] = o;
    }
  }
}

// ---------------------------------------------------------------------------
// Combine the two kv-split partials: ctx = (OA + OB) / (lA + lB).
// ---------------------------------------------------------------------------
__global__ __launch_bounds__(256) void combine_kernel(
    const unsigned short* __restrict__ Opart, const float* __restrict__ lbuf,
    unsigned short* __restrict__ ctx)
{
  int idx = blockIdx.x * 256 + threadIdx.x;   // 0 .. 2M-1
  int m = idx >> 9;                           // row 0..4095
  int c2 = idx & 511;
  int b = m >> 11, s = m & 2047;
  int h = c2 >> 5;
  int bh = b * 16 + h;
  float la = lbuf[bh * 2048 + s];
  float lb = lbuf[(32 + bh) * 2048 + s];
  float r = 1.0f / (la + lb);
  unsigned int ua = ((const unsigned int*)Opart)[idx];
  unsigned int ub = ((const unsigned int*)Opart)[(1u << 21) + idx];
  float o0 = (bfl(ua) + bfl(ub)) * r;
  float o1 = (bfh(ua) + bfh(ub)) * r;
  ((unsigned int*)ctx)[idx] = pkbf(o0, o1);
}

// ---------------------------------------------------------------------------
// O-projection (R7, passed four times): triple-buffered K-tiles with
// counted vmcnt + raw s_barrier. 64x128 tile, chunked XCD swizzle.
// fp32 out + bias.
// ---------------------------------------------------------------------------
__global__ __launch_bounds__(256) void gemm_o_bf(
    const unsigned short* __restrict__ X,
    const unsigned short* __restrict__ Wb,
    const float* __restrict__ bias,
    float* __restrict__ out)
{
  constexpr int K = 1024;
  __shared__ unsigned short As[3][64 * 32];
  __shared__ unsigned short Bs[3][128 * 32];
  const int id = blockIdx.x;
  const int sw_id = (id & 7) * 64 + (id >> 3);   // 512 = 8 x 64, bijective
  const int mBase = (sw_id >> 3) << 6, nBase = (sw_id & 7) << 7;

  const int tid = threadIdx.x;
  const int wave = tid >> 6, lane = tid & 63;
  const int quad = lane >> 4, l16 = lane & 15;
  const int wm = (wave >> 1) << 5, wn = (wave & 1) << 6;

  const int La = tid, ra = La >> 2, ca = ((La & 3) ^ (ra & 3)) << 3;
  const int Lb1 = 256 + tid, rb1 = Lb1 >> 2, cb1 = ((Lb1 & 3) ^ (rb1 & 3)) << 3;

  f32x4 acc[2][4] = {};

#define O_STAGE(kt, bi)                                                        \
  do {                                                                         \
    const int k0_ = (kt) * 32;                                                 \
    async_copy16(X + (size_t)(mBase + ra) * K + k0_ + ca, &As[bi][La * 8]);    \
    async_copy16(Wb + (size_t)(nBase + ra) * K + k0_ + ca, &Bs[bi][La * 8]);   \
    async_copy16(Wb + (size_t)(nBase + rb1) * K + k0_ + cb1, &Bs[bi][Lb1 * 8]);\
  } while (0)

  O_STAGE(0, 0);
  O_STAGE(1, 1);                   // 6 loads in flight

  const int sw = (quad ^ (l16 & 3)) << 3;
  for (int it = 0; it < 32; ++it) {
    if (it < 31)
      asm volatile("s_waitcnt vmcnt(3)" ::: "memory");   // oldest stage done
    else
      asm volatile("s_waitcnt vmcnt(0)" ::: "memory");
    __builtin_amdgcn_s_barrier();
    if (it < 30)
      O_STAGE(it + 2, (it + 2) % 3);
    const int cur = it % 3;
    bf16x8 af[2], bff[4];
#pragma unroll
    for (int t = 0; t < 2; ++t)
      af[t] = *(const bf16x8*)&As[cur][(wm + t * 16 + l16) * 32 + sw];
#pragma unroll
    for (int t = 0; t < 4; ++t)
      bff[t] = *(const bf16x8*)&Bs[cur][(wn + t * 16 + l16) * 32 + sw];
#pragma unroll
    for (int mt = 0; mt < 2; ++mt)
#pragma unroll
      for (int nt = 0; nt < 4; ++nt)
        acc[mt][nt] = __builtin_amdgcn_mfma_f32_16x16x32_bf16(af[mt], bff[nt], acc[mt][nt], 0, 0, 0);
  }
#undef O_STAGE

#pragma unroll
  for (int nt = 0; nt < 4; ++nt) {
    int n = nBase + wn + nt * 16 + l16;
    float bv = bias[n];
#pragma unroll
    for (int mt = 0; mt < 2; ++mt) {
#pragma unroll
      for (int j = 0; j < 4; ++j) {
        int m = mBase + wm + mt * 16 + quad * 4 + j;
        out[((size_t)m << 10) + n] = acc[mt][nt][j] + bv;
      }
    }
  }
}

// ---------------------------------------------------------------------------
// Memory plan (elem = bf16; 1M = 1<<20 elem = 2 MB):
//  ws (32 MB = 16M elem): w4 [0,4M) | k [4M,8M) | vT [8M,12M) | q [12M,16M)
//    - lbuf (fp32, 512 KB) overlays [0,256K elem) — wq dead by then
//    - ctx [12M,16M) overlays q after attn (q dead)
//  d_out (16 MB = 8M elem bf16 view): xqb [0,4M) | xkvb [4M,8M)
//    - attn partials OA [0,4M), OB [4M,8M) overlay (xqb/xkvb dead)
//    - final fp32 out overwrites everything (partials dead)
// All phases are stream-ordered; no region is concurrently read+written.
// RoPE is fused into gemm_qkv's epilogue (no separate pass).
// ---------------------------------------------------------------------------
extern "C" void kernel_launch(void* const* d_in, const int* in_sizes, int n_in,
                              void* d_out, int out_size, void* d_ws, size_t ws_size,
                              hipStream_t stream) {
  const float* x_q  = (const float*)d_in[0];
  const float* x_kv = (const float*)d_in[1];
  const float* wq   = (const float*)d_in[2];
  const float* bq   = (const float*)d_in[3];
  const float* wk   = (const float*)d_in[4];
  const float* bk   = (const float*)d_in[5];
  const float* wv   = (const float*)d_in[6];
  const float* bv   = (const float*)d_in[7];
  const float* wo   = (const float*)d_in[8];
  const float* bo   = (const float*)d_in[9];

  unsigned short* base = (unsigned short*)d_ws;
  unsigned short* ob   = (unsigned short*)d_out;

  unsigned short* wob  = base + (3u << 20);
  unsigned short* k    = base + (4u << 20);
  unsigned short* vT   = base + (8u << 20);
  unsigned short* q    = base + (12u << 20);
  unsigned short* ctx  = q;                    // overlays q after attn
  float*          lbuf = (float*)d_ws;         // overlays wq (dead)
  unsigned short* xqb  = ob;
  unsigned short* xkvb = ob + (4u << 20);
  unsigned short* Opart = ob;                  // overlays xqb/xkvb (dead)
  float* out = (float*)d_out;

  cvt8<<<12288, 256, 0, stream>>>(wq, wk, wv, wo, x_q, x_kv, base, ob);
  gemm_qkv_bf<<<1536, 256, 0, stream>>>(xqb, xkvb, base, bq, bk, bv, q, k, vT);
  attn_v9<<<512, 512, 0, stream>>>(q, k, vT, Opart, lbuf);
  combine_kernel<<<8192, 256, 0, stream>>>(Opart, lbuf, ctx);
  gemm_o_bf<<<512, 256, 0, stream>>>(ctx, wob, bo, out);
}

// Round 12
// 205.597 us; speedup vs baseline: 1.1071x; 1.0562x over previous
//
#include <hip/hip_runtime.h>
#include <cstdint>

typedef __attribute__((ext_vector_type(8))) short bf16x8;
typedef __attribute__((ext_vector_type(4))) float f32x4;
typedef __attribute__((ext_vector_type(4))) unsigned int u32x4;

#define DEV static __device__ __forceinline__

DEV unsigned short f2bf(float f) {
  unsigned int u = __builtin_bit_cast(unsigned int, f);
  u += 0x7FFFu + ((u >> 16) & 1u);
  return (unsigned short)(u >> 16);
}
#if __has_builtin(__builtin_amdgcn_cvt_pk_bf16_f32)
DEV unsigned int pkbf(float a, float b) {
  auto v = __builtin_amdgcn_cvt_pk_bf16_f32(a, b);
  return __builtin_bit_cast(unsigned int, v);
}
#else
DEV unsigned int pkbf(float a, float b) {
  return (unsigned int)f2bf(a) | ((unsigned int)f2bf(b) << 16);
}
#endif
#if __has_builtin(__builtin_amdgcn_exp2f)
#define EXP2(x) __builtin_amdgcn_exp2f(x)
#else
#define EXP2(x) exp2f(x)
#endif
DEV float bfl(unsigned int u) { return __builtin_bit_cast(float, u << 16); }
DEV float bfh(unsigned int u) { return __builtin_bit_cast(float, u & 0xFFFF0000u); }

DEV void async_copy16(const unsigned short* g, unsigned short* l) {
  __builtin_amdgcn_global_load_lds(
      (const __attribute__((address_space(1))) unsigned int*)(uintptr_t)g,
      (__attribute__((address_space(3))) unsigned int*)(uintptr_t)l,
      16, 0, 0);
}

// P-fragment lane redistribution for PV (T12). See R1 derivation.
#if __has_builtin(__builtin_amdgcn_permlane32_swap) && \
    __has_builtin(__builtin_amdgcn_permlane16_swap)
DEV void pswap(unsigned a, unsigned b, unsigned& w0, unsigned& w2, int lane) {
  (void)lane;
  auto pq = __builtin_amdgcn_permlane32_swap((int)a, (int)b, false, false);
  auto wz = __builtin_amdgcn_permlane16_swap(pq[0], pq[1], false, false);
  w0 = (unsigned)wz[0];
  w2 = (unsigned)wz[1];
}
#else
DEV void pswap(unsigned a, unsigned b, unsigned& w0, unsigned& w2, int lane) {
  int q = lane >> 4, l = lane & 15;
  int src0 = ((q & 1) << 5) + l;          // quads {0,2} of the source half
  int a0 = __shfl((int)a, src0), b0 = __shfl((int)b, src0);
  int a2 = __shfl((int)a, src0 + 16), b2 = __shfl((int)b, src0 + 16);
  w0 = (unsigned)(q < 2 ? a0 : b0);
  w2 = (unsigned)(q < 2 ? a2 : b2);
}
#endif

// ---------------------------------------------------------------------------
// cvt8: fp32 -> bf16 for wq,wk,wv,wo (ws elem [0,4M)) and x_q,x_kv
// (d_out bf16 view: xqb@[0,4M), xkvb@[4M,8M)). 3M threads, float4 each.
// ---------------------------------------------------------------------------
__global__ __launch_bounds__(256) void cvt8(
    const float* __restrict__ w0, const float* __restrict__ w1,
    const float* __restrict__ w2, const float* __restrict__ w3,
    const float* __restrict__ x0, const float* __restrict__ x1,
    unsigned short* __restrict__ wsb, unsigned short* __restrict__ xb)
{
  int id = blockIdx.x * 256 + threadIdx.x;      // 0 .. 3M-1
  const float* src;
  unsigned short* dp;
  int off;
  if (id < (1 << 20)) {
    int m = id >> 18;
    off = (id & 0x3FFFF) << 2;
    src = m == 0 ? w0 : m == 1 ? w1 : m == 2 ? w2 : w3;
    dp = wsb + (((size_t)m) << 20) + off;
  } else {
    int id2 = id - (1 << 20);
    int m = id2 >> 20;
    off = (id2 & 0xFFFFF) << 2;
    src = m ? x1 : x0;
    dp = xb + (((size_t)m) << 22) + off;
  }
  float4 v = *(const float4*)(src + off);
  uint2 o;
  o.x = pkbf(v.x, v.y);
  o.y = pkbf(v.z, v.w);
  *(uint2*)dp = o;
}

// ---------------------------------------------------------------------------
// QKV projection (R11, verified): BK=64, 128B LDS rows + 8-chunk XOR
// (^row&7) — conflict-free geometry; 16 iters, 2-phase double-buffer,
// 64x128 tile, XCD-chunked decode, grid 1536 -> 3 blocks/CU at 48KB LDS.
// z<2 -> [bh][s][64] with RoPE fused in the epilogue (sincosf SINE-FIRST);
// Q scaled by 0.125*log2(e). z==2 -> V^T [bh][hd][s].
// ---------------------------------------------------------------------------
__global__ __launch_bounds__(256) void gemm_qkv_bf(
    const unsigned short* __restrict__ xqb,
    const unsigned short* __restrict__ xkvb,
    const unsigned short* __restrict__ wbase,
    const float* __restrict__ bq, const float* __restrict__ bk,
    const float* __restrict__ bv,
    unsigned short* __restrict__ outq, unsigned short* __restrict__ outk,
    unsigned short* __restrict__ outvT)
{
  constexpr int K = 1024;
  __shared__ unsigned short As[2][64 * 64];     // 8 KB / buf
  __shared__ unsigned short Bs[2][128 * 64];    // 16 KB / buf
  const int id = blockIdx.x;
  const int sw_id = (id & 7) * 192 + (id >> 3);
  const int z = sw_id >> 9;                      // 512 tiles per z
  const int r = sw_id & 511;
  const int mBase = (r >> 3) << 6, nBase = (r & 7) << 7;

  const unsigned short* X = (z == 0) ? xqb : xkvb;
  const unsigned short* Wb = wbase + (((size_t)z) << 20);
  const float* bias = (z == 0) ? bq : (z == 1) ? bk : bv;

  const int tid = threadIdx.x;
  const int wave = tid >> 6, lane = tid & 63;
  const int quad = lane >> 4, l16 = lane & 15;
  const int wm = (wave >> 1) << 5, wn = (wave & 1) << 6;

  // staging (16B chunks, 8 per 64-elem row; LDS linear, source pre-swizzled):
  // A: 512 chunks = 2/thread; B: 1024 chunks = 4/thread.
  const int La0 = tid, La1 = 256 + tid;
  const int ra0 = La0 >> 3, ca0 = ((La0 & 7) ^ (ra0 & 7)) << 3;
  const int ra1 = La1 >> 3, ca1 = ((La1 & 7) ^ (ra1 & 7)) << 3;
  const int Lb0 = tid,        rb0 = Lb0 >> 3, cb0 = ((Lb0 & 7) ^ (rb0 & 7)) << 3;
  const int Lb1 = 256 + tid,  rb1 = Lb1 >> 3, cb1 = ((Lb1 & 7) ^ (rb1 & 7)) << 3;
  const int Lb2 = 512 + tid,  rb2 = Lb2 >> 3, cb2 = ((Lb2 & 7) ^ (rb2 & 7)) << 3;
  const int Lb3 = 768 + tid,  rb3 = Lb3 >> 3, cb3 = ((Lb3 & 7) ^ (rb3 & 7)) << 3;

  f32x4 acc[2][4] = {};

#define QKV_STAGE(kt, bi)                                                      \
  do {                                                                         \
    const int k0_ = (kt) * 64;                                                 \
    async_copy16(X + (size_t)(mBase + ra0) * K + k0_ + ca0, &As[bi][La0 * 8]); \
    async_copy16(X + (size_t)(mBase + ra1) * K + k0_ + ca1, &As[bi][La1 * 8]); \
    async_copy16(Wb + (size_t)(nBase + rb0) * K + k0_ + cb0, &Bs[bi][Lb0 * 8]);\
    async_copy16(Wb + (size_t)(nBase + rb1) * K + k0_ + cb1, &Bs[bi][Lb1 * 8]);\
    async_copy16(Wb + (size_t)(nBase + rb2) * K + k0_ + cb2, &Bs[bi][Lb2 * 8]);\
    async_copy16(Wb + (size_t)(nBase + rb3) * K + k0_ + cb3, &Bs[bi][Lb3 * 8]);\
  } while (0)

  QKV_STAGE(0, 0);
  __syncthreads();

  const int swz = l16 & 7;
  for (int it = 0; it < 16; ++it) {
    const int cur = it & 1;
    if (it < 15)
      QKV_STAGE(it + 1, cur ^ 1);
#pragma unroll
    for (int kd = 0; kd < 2; ++kd) {
      const int cs = (((kd * 4 + quad) ^ swz) << 3);
      bf16x8 af[2], bff[4];
#pragma unroll
      for (int t = 0; t < 2; ++t)
        af[t] = *(const bf16x8*)&As[cur][(wm + t * 16 + l16) * 64 + cs];
#pragma unroll
      for (int t = 0; t < 4; ++t)
        bff[t] = *(const bf16x8*)&Bs[cur][(wn + t * 16 + l16) * 64 + cs];
#pragma unroll
      for (int mt = 0; mt < 2; ++mt)
#pragma unroll
        for (int nt = 0; nt < 4; ++nt)
          acc[mt][nt] = __builtin_amdgcn_mfma_f32_16x16x32_bf16(af[mt], bff[nt], acc[mt][nt], 0, 0, 0);
    }
    __syncthreads();   // drains prefetch vmcnt + protects cur buffer
  }
#undef QKV_STAGE

  if (z < 2) {
    unsigned short* out = z ? outk : outq;
    const float qs = z ? 1.0f : 0.18033688011112042f;  // 0.125*log2(e)
    const int sBlk = (mBase & 2047) + wm + quad * 4;   // s at mt=0, j=0
#pragma unroll
    for (int nt = 0; nt < 4; ++nt) {
      int n = nBase + wn + nt * 16 + l16;
      float bv2 = bias[n];
      int h = n >> 6, hd = n & 63;
      int i = hd >> 1;
      int parity = n & 1;
      float f = exp2f(-(float)i * 0.4152410118609203f);
      float sf, cf;
      sincosf(f, &sf, &cf);
#pragma unroll
      for (int mt = 0; mt < 2; ++mt) {
        float ang = (float)(sBlk + mt * 16) * f;
        float s, c;
        sincosf(ang, &s, &c);
#pragma unroll
        for (int j = 0; j < 4; ++j) {
          float v = acc[mt][nt][j] + bv2;
          float pv = __shfl_xor(v, 1);
          float ce = c * qs;
          float se = (parity ? s : -s) * qs;
          float outv = v * ce + pv * se;
          int m = mBase + wm + mt * 16 + quad * 4 + j;
          int b = m >> 11, sv = m & 2047;
          out[(((size_t)(b * 16 + h) * 2048 + sv) << 6) + hd] = f2bf(outv);
          float c2 = c * cf - s * sf;
          s = s * cf + c * sf;
          c = c2;
        }
      }
    }
  } else {
#pragma unroll
    for (int nt = 0; nt < 4; ++nt) {
      int n = nBase + wn + nt * 16 + l16;
      float bv2 = bias[n];
      int h = n >> 6, hd = n & 63;
#pragma unroll
      for (int mt = 0; mt < 2; ++mt) {
        int m0 = mBase + wm + mt * 16 + quad * 4;
        int b = m0 >> 11, s = m0 & 2047;
        uint2 o;
        o.x = pkbf(acc[mt][nt][0] + bv2, acc[mt][nt][1] + bv2);
        o.y = pkbf(acc[mt][nt][2] + bv2, acc[mt][nt][3] + bv2);
        *(uint2*)&outvT[(((size_t)(b * 16 + h) * 64 + hd) << 11) + s] = o;
      }
    }
  }
}

// ---------------------------------------------------------------------------
// Flash attention v9 (R10/R11, passed): 8 waves/block, ones-MFMA l
// accumulation, deferred PV (V triple-buffer), rule-21 swizzle, in-reg P,
// setprio. Grid 512 = bh(32) x qt(8) x kvs(2) -> 2 blocks/CU x 8 waves.
// ---------------------------------------------------------------------------
__global__ __launch_bounds__(512) void attn_v9(
    const unsigned short* __restrict__ Qg,
    const unsigned short* __restrict__ Kg,
    const unsigned short* __restrict__ VT,
    unsigned short* __restrict__ Opart,   // [kvs][4096][1024] bf16
    float* __restrict__ lbuf)             // [kvs][32][2048]
{
  __shared__ unsigned short Ks[2][64 * 64];
  __shared__ unsigned short Vs[3][64 * 64];
  const int tid = threadIdx.x, wave = tid >> 6, lane = tid & 63;
  const int quad = lane >> 4, l16 = lane & 15;
  const int bh = blockIdx.x & 31;            // id%8 = bh%8 -> same-bh on XCD
  const int qt = (blockIdx.x >> 5) & 7;
  const int kvs = blockIdx.x >> 8;           // 0/1
  const int q0 = qt * 256 + wave * 32;
  const unsigned short* Qb = Qg + ((size_t)bh << 17);
  const unsigned short* Kb = Kg + ((size_t)bh << 17);
  const unsigned short* Vb = VT + ((size_t)bh << 17);

  // staging: 1 chunk of K + 1 chunk of V per thread (512 threads = 512 chunks)
  const int L0 = tid;
  const int r0 = L0 >> 3;
  const int c0 = ((L0 & 7) ^ (r0 & 7)) << 3;

  bf16x8 qf[2][2];
#pragma unroll
  for (int mq = 0; mq < 2; ++mq)
#pragma unroll
    for (int kd = 0; kd < 2; ++kd)
      qf[mq][kd] = *(const bf16x8*)(Qb + (size_t)(q0 + mq * 16 + l16) * 64 + kd * 32 + quad * 8);

  bf16x8 onesf;
#pragma unroll
  for (int i = 0; i < 8; ++i) onesf[i] = (short)0x3F80;

  f32x4 oacc[4][2] = {};                     // [th(hd)][mq(q)]
  f32x4 laccv[2] = {};                       // l via ones-MFMA, [mq]
  bf16x8 pfp[2][2];                          // carried P frags [ks][mq]

  const int kvbeg = kvs << 10;
  const int swz = l16 & 7;

  async_copy16(Kb + (size_t)(kvbeg + r0) * 64 + c0, &Ks[0][L0 * 8]);
  async_copy16(Vb + (size_t)r0 * 2048 + kvbeg + c0, &Vs[0][L0 * 8]);
  __syncthreads();

  for (int t = 0; t < 16; ++t) {
    const int kcur = t & 1;
    if (t < 15) {                            // stage tile t+1
      const int kv0 = kvbeg + (t + 1) * 64;
      async_copy16(Kb + (size_t)(kv0 + r0) * 64 + c0, &Ks[kcur ^ 1][L0 * 8]);
      async_copy16(Vb + (size_t)r0 * 2048 + kv0 + c0, &Vs[(t + 1) % 3][L0 * 8]);
    }

    // --- deferred PV(t-1): fills the QK ds_read shadow ---
    if (t > 0) {
      const unsigned short* Vp = Vs[(t - 1) % 3];
      __builtin_amdgcn_s_setprio(1);
#pragma unroll
      for (int ks = 0; ks < 2; ++ks) {
#pragma unroll
        for (int th = 0; th < 4; ++th) {
          bf16x8 vf = *(const bf16x8*)&Vp[(th * 16 + l16) * 64 + (((ks * 4 + quad) ^ swz) << 3)];
#pragma unroll
          for (int mq = 0; mq < 2; ++mq)
            oacc[th][mq] = __builtin_amdgcn_mfma_f32_16x16x32_bf16(vf, pfp[ks][mq], oacc[th][mq], 0, 0, 0);
        }
#pragma unroll
        for (int mq = 0; mq < 2; ++mq)
          laccv[mq] = __builtin_amdgcn_mfma_f32_16x16x32_bf16(onesf, pfp[ks][mq], laccv[mq], 0, 0, 0);
      }
      __builtin_amdgcn_s_setprio(0);
    }

    // --- S^T = K·Q^T (swizzled ds_read) ---
    const unsigned short* Kc = Ks[kcur];
    f32x4 st[4][2] = {};
    __builtin_amdgcn_s_setprio(1);
#pragma unroll
    for (int kd = 0; kd < 2; ++kd)
#pragma unroll
      for (int tk = 0; tk < 4; ++tk) {
        bf16x8 kf = *(const bf16x8*)&Kc[(tk * 16 + l16) * 64 + (((kd * 4 + quad) ^ swz) << 3)];
#pragma unroll
        for (int mq = 0; mq < 2; ++mq)
          st[tk][mq] = __builtin_amdgcn_mfma_f32_16x16x32_bf16(kf, qf[mq][kd], st[tk][mq], 0, 0, 0);
      }
    __builtin_amdgcn_s_setprio(0);

    // --- static softmax: p = exp2(st); pack P frags for next-iter PV ---
#pragma unroll
    for (int mq = 0; mq < 2; ++mq)
#pragma unroll
      for (int tk = 0; tk < 4; ++tk)
#pragma unroll
        for (int jr = 0; jr < 4; ++jr)
          st[tk][mq][jr] = EXP2(st[tk][mq][jr]);

#pragma unroll
    for (int ks = 0; ks < 2; ++ks)
#pragma unroll
      for (int mq = 0; mq < 2; ++mq) {
        u32x4 pw;
#pragma unroll
        for (int w = 0; w < 2; ++w) {
          unsigned a = pkbf(st[2 * ks][mq][2 * w], st[2 * ks][mq][2 * w + 1]);
          unsigned b = pkbf(st[2 * ks + 1][mq][2 * w], st[2 * ks + 1][mq][2 * w + 1]);
          unsigned w0, w2;
          pswap(a, b, w0, w2, lane);
          pw[w] = w0;
          pw[w + 2] = w2;
        }
        pfp[ks][mq] = __builtin_bit_cast(bf16x8, pw);
      }

    __syncthreads();   // orders stage(t+1) vs reads at t+1; protects buffers
  }

  // --- final PV(15): V tile 15 lives in Vs[0] ---
  {
    const unsigned short* Vp = Vs[15 % 3];
    __builtin_amdgcn_s_setprio(1);
#pragma unroll
    for (int ks = 0; ks < 2; ++ks) {
#pragma unroll
      for (int th = 0; th < 4; ++th) {
        bf16x8 vf = *(const bf16x8*)&Vp[(th * 16 + l16) * 64 + (((ks * 4 + quad) ^ swz) << 3)];
#pragma unroll
        for (int mq = 0; mq < 2; ++mq)
          oacc[th][mq] = __builtin_amdgcn_mfma_f32_16x16x32_bf16(vf, pfp[ks][mq], oacc[th][mq], 0, 0, 0);
      }
#pragma unroll
      for (int mq = 0; mq < 2; ++mq)
        laccv[mq] = __builtin_amdgcn_mfma_f32_16x16x32_bf16(onesf, pfp[ks][mq], laccv[mq], 0, 0, 0);
    }
    __builtin_amdgcn_s_setprio(0);
  }

  // --- epilogue: write partial l (quad 0) and unnormalized partial O ---
  const int b = bh >> 4, h = bh & 15;
  unsigned short* Od = Opart + (((size_t)kvs) << 22);
#pragma unroll
  for (int mq = 0; mq < 2; ++mq) {
    int s = q0 + mq * 16 + l16;
    if (quad == 0)
      lbuf[(kvs * 32 + bh) * 2048 + s] = laccv[mq][0];
#pragma unroll
    for (int th = 0; th < 4; ++th) {
      uint2 o;
      o.x = pkbf(oacc[th][mq][0], oacc[th][mq][1]);
      o.y = pkbf(oacc[th][mq][2], oacc[th][mq][3]);
      *(uint2*)&Od[((size_t)(b * 2048 + s) << 10) + h * 64 + th * 16 + quad * 4] = o;
    }
  }
}

// ---------------------------------------------------------------------------
// Combine the two kv-split partials: ctx = (OA + OB) / (lA + lB).
// ---------------------------------------------------------------------------
__global__ __launch_bounds__(256) void combine_kernel(
    const unsigned short* __restrict__ Opart, const float* __restrict__ lbuf,
    unsigned short* __restrict__ ctx)
{
  int idx = blockIdx.x * 256 + threadIdx.x;   // 0 .. 2M-1
  int m = idx >> 9;                           // row 0..4095
  int c2 = idx & 511;
  int b = m >> 11, s = m & 2047;
  int h = c2 >> 5;
  int bh = b * 16 + h;
  float la = lbuf[bh * 2048 + s];
  float lb = lbuf[(32 + bh) * 2048 + s];
  float r = 1.0f / (la + lb);
  unsigned int ua = ((const unsigned int*)Opart)[idx];
  unsigned int ub = ((const unsigned int*)Opart)[(1u << 21) + idx];
  float o0 = (bfl(ua) + bfl(ub)) * r;
  float o1 = (bfh(ua) + bfh(ub)) * r;
  ((unsigned int*)ctx)[idx] = pkbf(o0, o1);
}

// ---------------------------------------------------------------------------
// O-projection. R12: converted to the R11-verified conflict-free geometry —
// BK=64, 128B LDS rows + 8-chunk XOR (^row&7), 2-phase double-buffer,
// 16 iters (R7's null counted-vmcnt machinery dropped). 64x128 tile,
// grid 512 XCD-chunked, LDS 48KB -> 3 blocks/CU. fp32 out + bias.
// ---------------------------------------------------------------------------
__global__ __launch_bounds__(256) void gemm_o_bf(
    const unsigned short* __restrict__ X,
    const unsigned short* __restrict__ Wb,
    const float* __restrict__ bias,
    float* __restrict__ out)
{
  constexpr int K = 1024;
  __shared__ unsigned short As[2][64 * 64];     // 8 KB / buf
  __shared__ unsigned short Bs[2][128 * 64];    // 16 KB / buf
  const int id = blockIdx.x;
  const int sw_id = (id & 7) * 64 + (id >> 3);   // 512 = 8 x 64, bijective
  const int mBase = (sw_id >> 3) << 6, nBase = (sw_id & 7) << 7;

  const int tid = threadIdx.x;
  const int wave = tid >> 6, lane = tid & 63;
  const int quad = lane >> 4, l16 = lane & 15;
  const int wm = (wave >> 1) << 5, wn = (wave & 1) << 6;

  // staging (16B chunks, 8 per 64-elem row; LDS linear, source pre-swizzled):
  // A: 512 chunks = 2/thread; B: 1024 chunks = 4/thread.
  const int La0 = tid, La1 = 256 + tid;
  const int ra0 = La0 >> 3, ca0 = ((La0 & 7) ^ (ra0 & 7)) << 3;
  const int ra1 = La1 >> 3, ca1 = ((La1 & 7) ^ (ra1 & 7)) << 3;
  const int Lb0 = tid,        rb0 = Lb0 >> 3, cb0 = ((Lb0 & 7) ^ (rb0 & 7)) << 3;
  const int Lb1 = 256 + tid,  rb1 = Lb1 >> 3, cb1 = ((Lb1 & 7) ^ (rb1 & 7)) << 3;
  const int Lb2 = 512 + tid,  rb2 = Lb2 >> 3, cb2 = ((Lb2 & 7) ^ (rb2 & 7)) << 3;
  const int Lb3 = 768 + tid,  rb3 = Lb3 >> 3, cb3 = ((Lb3 & 7) ^ (rb3 & 7)) << 3;

  f32x4 acc[2][4] = {};

#define O_STAGE(kt, bi)                                                        \
  do {                                                                         \
    const int k0_ = (kt) * 64;                                                 \
    async_copy16(X + (size_t)(mBase + ra0) * K + k0_ + ca0, &As[bi][La0 * 8]); \
    async_copy16(X + (size_t)(mBase + ra1) * K + k0_ + ca1, &As[bi][La1 * 8]); \
    async_copy16(Wb + (size_t)(nBase + rb0) * K + k0_ + cb0, &Bs[bi][Lb0 * 8]);\
    async_copy16(Wb + (size_t)(nBase + rb1) * K + k0_ + cb1, &Bs[bi][Lb1 * 8]);\
    async_copy16(Wb + (size_t)(nBase + rb2) * K + k0_ + cb2, &Bs[bi][Lb2 * 8]);\
    async_copy16(Wb + (size_t)(nBase + rb3) * K + k0_ + cb3, &Bs[bi][Lb3 * 8]);\
  } while (0)

  O_STAGE(0, 0);
  __syncthreads();

  const int swz = l16 & 7;
  for (int it = 0; it < 16; ++it) {
    const int cur = it & 1;
    if (it < 15)
      O_STAGE(it + 1, cur ^ 1);
#pragma unroll
    for (int kd = 0; kd < 2; ++kd) {
      const int cs = (((kd * 4 + quad) ^ swz) << 3);
      bf16x8 af[2], bff[4];
#pragma unroll
      for (int t = 0; t < 2; ++t)
        af[t] = *(const bf16x8*)&As[cur][(wm + t * 16 + l16) * 64 + cs];
#pragma unroll
      for (int t = 0; t < 4; ++t)
        bff[t] = *(const bf16x8*)&Bs[cur][(wn + t * 16 + l16) * 64 + cs];
#pragma unroll
      for (int mt = 0; mt < 2; ++mt)
#pragma unroll
        for (int nt = 0; nt < 4; ++nt)
          acc[mt][nt] = __builtin_amdgcn_mfma_f32_16x16x32_bf16(af[mt], bff[nt], acc[mt][nt], 0, 0, 0);
    }
    __syncthreads();   // drains prefetch vmcnt + protects cur buffer
  }
#undef O_STAGE

#pragma unroll
  for (int nt = 0; nt < 4; ++nt) {
    int n = nBase + wn + nt * 16 + l16;
    float bv = bias[n];
#pragma unroll
    for (int mt = 0; mt < 2; ++mt) {
#pragma unroll
      for (int j = 0; j < 4; ++j) {
        int m = mBase + wm + mt * 16 + quad * 4 + j;
        out[((size_t)m << 10) + n] = acc[mt][nt][j] + bv;
      }
    }
  }
}

// ---------------------------------------------------------------------------
// Memory plan (elem = bf16; 1M = 1<<20 elem = 2 MB):
//  ws (32 MB = 16M elem): w4 [0,4M) | k [4M,8M) | vT [8M,12M) | q [12M,16M)
//    - lbuf (fp32, 512 KB) overlays [0,256K elem) — wq dead by then
//    - ctx [12M,16M) overlays q after attn (q dead)
//  d_out (16 MB = 8M elem bf16 view): xqb [0,4M) | xkvb [4M,8M)
//    - attn partials OA [0,4M), OB [4M,8M) overlay (xqb/xkvb dead)
//    - final fp32 out overwrites everything (partials dead)
// All phases are stream-ordered; no region is concurrently read+written.
// RoPE is fused into gemm_qkv's epilogue (no separate pass).
// ---------------------------------------------------------------------------
extern "C" void kernel_launch(void* const* d_in, const int* in_sizes, int n_in,
                              void* d_out, int out_size, void* d_ws, size_t ws_size,
                              hipStream_t stream) {
  const float* x_q  = (const float*)d_in[0];
  const float* x_kv = (const float*)d_in[1];
  const float* wq   = (const float*)d_in[2];
  const float* bq   = (const float*)d_in[3];
  const float* wk   = (const float*)d_in[4];
  const float* bk   = (const float*)d_in[5];
  const float* wv   = (const float*)d_in[6];
  const float* bv   = (const float*)d_in[7];
  const float* wo   = (const float*)d_in[8];
  const float* bo   = (const float*)d_in[9];

  unsigned short* base = (unsigned short*)d_ws;
  unsigned short* ob   = (unsigned short*)d_out;

  unsigned short* wob  = base + (3u << 20);
  unsigned short* k    = base + (4u << 20);
  unsigned short* vT   = base + (8u << 20);
  unsigned short* q    = base + (12u << 20);
  unsigned short* ctx  = q;                    // overlays q after attn
  float*          lbuf = (float*)d_ws;         // overlays wq (dead)
  unsigned short* xqb  = ob;
  unsigned short* xkvb = ob + (4u << 20);
  unsigned short* Opart = ob;                  // overlays xqb/xkvb (dead)
  float* out = (float*)d_out;

  cvt8<<<12288, 256, 0, stream>>>(wq, wk, wv, wo, x_q, x_kv, base, ob);
  gemm_qkv_bf<<<1536, 256, 0, stream>>>(xqb, xkvb, base, bq, bk, bv, q, k, vT);
  attn_v9<<<512, 512, 0, stream>>>(q, k, vT, Opart, lbuf);
  combine_kernel<<<8192, 256, 0, stream>>>(Opart, lbuf, ctx);
  gemm_o_bf<<<512, 256, 0, stream>>>(ctx, wob, bo, out);
}